// Round 7
// baseline (206.674 us; speedup 1.0000x reference)
//
#include <hip/hip_runtime.h>

#define PP 10
#define LL 6
#define NIMG 4
#define HW (1024*1024)
#define NBO 59    // 45 inter(l=1..5,p=1..9) + 9 pred_area(p=1..9) + 5 cnt(l=1..5)
#define BX 256    // blocks per image
#define TPB 256
#define ITERS 4   // HW/4 / (BX*TPB) = 4, exact

// ws layout (TRANSPOSED for coalesced finalize):
//   part[img][b][bx] = ws[(img*NBO + b)*BX + bx]

__global__ __launch_bounds__(TPB, 4) void accum_kernel(
    const float* __restrict__ pred,
    const int*   __restrict__ pconn,
    const int*   __restrict__ lconn,
    float*       __restrict__ ws)
{
    __shared__ float ld[NBO * 64];   // reduction staging only, 15.1 KB

    const int tid = threadIdx.x;
    const int img = blockIdx.y;
    const size_t base = (size_t)img * HW;

    const float4* __restrict__ p4  = (const float4*)(pred  + base);
    const int4*   __restrict__ pc4 = (const int4*)(pconn + base);
    const int4*   __restrict__ lc4 = (const int4*)(lconn + base);

    const int v0 = blockIdx.x * TPB + tid;
    const int stride = BX * TPB;   // 65536 vec4s

    // 59 register accumulators.
    float A[45];    // inter[l=1..5][p=1..9]: A[(l-1)*9 + (p-1)]
    float PA[9];    // pred_area[p=1..9] over ALL l
    float CNT[5];   // label_area[l=1..5]
#pragma unroll
    for (int i = 0; i < 45; ++i) A[i] = 0.0f;
#pragma unroll
    for (int i = 0; i < 9; ++i) PA[i] = 0.0f;
#pragma unroll
    for (int i = 0; i < 5; ++i) CNT[i] = 0.0f;

    // No manual prefetch: keep live set ~90 regs under the 128 cap
    // (R5 lesson: spill costs 100+ µs; TLP at 16 waves/CU hides latency).
#pragma unroll
    for (int i = 0; i < ITERS; ++i) {
        const int v = v0 + i * stride;
        const float4 p  = p4[v];
        const int4   pc = pc4[v];
        const int4   lc = lc4[v];
#pragma unroll
        for (int c = 0; c < 4; ++c) {
            const float pv  = (c == 0) ? p.x  : (c == 1) ? p.y  : (c == 2) ? p.z  : p.w;
            const int   lcv = (c == 0) ? lc.x : (c == 1) ? lc.y : (c == 2) ? lc.z : lc.w;
            const int   pcv = (c == 0) ? pc.x : (c == 1) ? pc.y : (c == 2) ? pc.z : pc.w;

            float op[PP];  // one-hot for p=1..9 only
#pragma unroll
            for (int q = 1; q < PP; ++q) op[q] = (pcv == q) ? 1.0f : 0.0f;
#pragma unroll
            for (int q = 1; q < PP; ++q) PA[q - 1] = fmaf(pv, op[q], PA[q - 1]);
#pragma unroll
            for (int l = 1; l < LL; ++l) {
                const bool ol = (lcv == l);
                CNT[l - 1] += ol ? 1.0f : 0.0f;
                const float hl = ol ? pv : 0.0f;
#pragma unroll
                for (int q = 1; q < PP; ++q)
                    A[(l - 1) * 9 + (q - 1)] = fmaf(hl, op[q], A[(l - 1) * 9 + (q - 1)]);
            }
        }
    }

    // Quad shuffle-reduce (4->1), stage into ld[bin*64 + unit].
    const int unit = (tid >> 6) * 16 + ((tid & 63) >> 2);  // 0..63
    const bool writer = ((tid & 3) == 0);
#pragma unroll
    for (int b = 0; b < 45; ++b) {
        float s = A[b];
        s += __shfl_down(s, 1, 64); s += __shfl_down(s, 2, 64);
        if (writer) ld[b * 64 + unit] = s;
    }
#pragma unroll
    for (int b = 0; b < 9; ++b) {
        float s = PA[b];
        s += __shfl_down(s, 1, 64); s += __shfl_down(s, 2, 64);
        if (writer) ld[(45 + b) * 64 + unit] = s;
    }
#pragma unroll
    for (int b = 0; b < 5; ++b) {
        float s = CNT[b];
        s += __shfl_down(s, 1, 64); s += __shfl_down(s, 2, 64);
        if (writer) ld[(54 + b) * 64 + unit] = s;
    }
    __syncthreads();

    // Threads 0..58: sum own row of 64 (rotated float4 reads), store
    // TRANSPOSED partial: bin-major, bx contiguous.
    if (tid < NBO) {
        const float4* row = (const float4*)(ld + tid * 64);
        float s = 0.0f;
#pragma unroll
        for (int i = 0; i < 16; ++i) {
            const float4 t4 = row[(i + tid) & 15];
            s += t4.x + t4.y + t4.z + t4.w;
        }
        ws[((size_t)img * NBO + tid) * BX + blockIdx.x] = s;
    }
}

__global__ __launch_bounds__(1024) void finalize_kernel(
    const float* __restrict__ ws, float* __restrict__ out)
{
    __shared__ float red[NIMG * NBO];   // 236
    __shared__ float contrib[NIMG];
    const int t = threadIdx.x;

    // 236 rows x 256 floats, contiguous: 4 threads/row, 16 float4 each.
    const int row = t >> 2, q = t & 3;
    if (row < NIMG * NBO) {
        const float4* basep = (const float4*)(ws + (size_t)row * BX + q * 64);
        float s = 0.0f;
#pragma unroll
        for (int i = 0; i < 16; ++i) {
            const float4 v = basep[i];
            s += v.x + v.y + v.z + v.w;
        }
        s += __shfl_down(s, 1, 64);
        s += __shfl_down(s, 2, 64);
        if (q == 0) red[row] = s;
    }
    __syncthreads();

    if (t < NIMG) {
        const float* b = red + t * NBO;
        // b[0..44]=inter(l-1,p-1), b[45..53]=pred_area(p-1), b[54..58]=label_area(l-1)
        float colsum[9];
#pragma unroll
        for (int p = 0; p < 9; ++p) colsum[p] = 0.0f;
        float pair_conn_sum = 0.0f;
        for (int l = 0; l < 5; ++l) {
            const float la = b[54 + l];
            float pc = 0.0f; int pn = 0;
            for (int p = 0; p < 9; ++p) {
                const float in = b[l * 9 + p];
                const float un = la + b[45 + p] - in;
                float iou;
                if (in == 0.0f)      iou = 0.0f;
                else if (un == 0.0f) iou = 1.0f;
                else                 iou = in / un;
                colsum[p] += iou;
                pc += iou;
                pn += (iou != 0.0f) ? 1 : 0;
            }
            if (pn > 0) pair_conn_sum += pc / (float)pn;
        }
        int lone = 0;
        for (int p = 0; p < 9; ++p) lone += (colsum[p] == 0.0f) ? 1 : 0;
        contrib[t] = 1.0f - pair_conn_sum / (5.0f + (float)lone);
    }
    __syncthreads();
    if (t == 0)
        out[0] = (contrib[0] + contrib[1] + contrib[2] + contrib[3]) * 0.25f;
}

extern "C" void kernel_launch(void* const* d_in, const int* in_sizes, int n_in,
                              void* d_out, int out_size, void* d_ws, size_t ws_size,
                              hipStream_t stream) {
    const float* pred  = (const float*)d_in[0];
    const int*   pconn = (const int*)d_in[1];
    const int*   lconn = (const int*)d_in[2];
    float* out = (float*)d_out;
    float* ws  = (float*)d_ws;

    dim3 grid(BX, NIMG);
    accum_kernel<<<grid, TPB, 0, stream>>>(pred, pconn, lconn, ws);

    finalize_kernel<<<1, 1024, 0, stream>>>(ws, out);
}

// Round 8
// 112.847 us; speedup vs baseline: 1.8314x; 1.8314x over previous
//
#include <hip/hip_runtime.h>

#define PP 10
#define LL 6
#define NIMG 4
#define HW (1024*1024)
#define NBO 59    // 45 inter(l=1..5,p=1..9) + 9 pred_area(p=1..9) + 5 cnt(l=1..5)
#define BX 256    // blocks per image
#define TPB 256
#define ITERS 4   // HW/4 / (BX*TPB) = 4, exact

// ws layout (TRANSPOSED for coalesced finalize):
//   part[img][b][bx] = ws[(img*NBO + b)*BX + bx]

// NOTE: no min-waves hint in __launch_bounds__ — R5 (=3) and R7 (=4) both
// made the allocator clamp VGPRs (84/64) and spill ~200 MB to scratch.
__global__ __launch_bounds__(TPB) void accum_kernel(
    const float* __restrict__ pred,
    const int*   __restrict__ pconn,
    const int*   __restrict__ lconn,
    float*       __restrict__ ws)
{
    __shared__ float ld[NBO * 64];   // reduction staging only, 15.1 KB

    const int tid = threadIdx.x;
    const int img = blockIdx.y;
    const size_t base = (size_t)img * HW;

    const float4* __restrict__ p4  = (const float4*)(pred  + base);
    const int4*   __restrict__ pc4 = (const int4*)(pconn + base);
    const int4*   __restrict__ lc4 = (const int4*)(lconn + base);

    const int v0 = blockIdx.x * TPB + tid;
    const int stride = BX * TPB;   // 65536 vec4s

    // 59 register accumulators.
    float A[45];    // inter[l=1..5][p=1..9]: A[(l-1)*9 + (p-1)]
    float PA[9];    // pred_area[p=1..9] over ALL l
    float CNT[5];   // label_area[l=1..5]
#pragma unroll
    for (int i = 0; i < 45; ++i) A[i] = 0.0f;
#pragma unroll
    for (int i = 0; i < 9; ++i) PA[i] = 0.0f;
#pragma unroll
    for (int i = 0; i < 5; ++i) CNT[i] = 0.0f;

    // One-ahead software pipeline (R6-proven): 2 vec4-triples live max.
    float4 pcur = p4[v0];
    int4   pccur = pc4[v0];
    int4   lccur = lc4[v0];

#pragma unroll
    for (int i = 0; i < ITERS; ++i) {
        float4 pnxt; int4 pcnxt, lcnxt;
        if (i + 1 < ITERS) {
            const int v = v0 + (i + 1) * stride;
            pnxt  = p4[v];
            pcnxt = pc4[v];
            lcnxt = lc4[v];
        }
#pragma unroll
        for (int c = 0; c < 4; ++c) {
            const float pv  = (c == 0) ? pcur.x  : (c == 1) ? pcur.y  : (c == 2) ? pcur.z  : pcur.w;
            const int   lcv = (c == 0) ? lccur.x : (c == 1) ? lccur.y : (c == 2) ? lccur.z : lccur.w;
            const int   pcv = (c == 0) ? pccur.x : (c == 1) ? pccur.y : (c == 2) ? pccur.z : pccur.w;

            float op[PP];  // one-hot for p=1..9 only
#pragma unroll
            for (int q = 1; q < PP; ++q) op[q] = (pcv == q) ? 1.0f : 0.0f;
#pragma unroll
            for (int q = 1; q < PP; ++q) PA[q - 1] = fmaf(pv, op[q], PA[q - 1]);
#pragma unroll
            for (int l = 1; l < LL; ++l) {
                const bool ol = (lcv == l);
                CNT[l - 1] += ol ? 1.0f : 0.0f;
                const float hl = ol ? pv : 0.0f;
#pragma unroll
                for (int q = 1; q < PP; ++q)
                    A[(l - 1) * 9 + (q - 1)] = fmaf(hl, op[q], A[(l - 1) * 9 + (q - 1)]);
            }
        }
        pcur = pnxt; pccur = pcnxt; lccur = lcnxt;
    }

    // Quad shuffle-reduce (4->1), stage into ld[bin*64 + unit].
    const int unit = (tid >> 6) * 16 + ((tid & 63) >> 2);  // 0..63
    const bool writer = ((tid & 3) == 0);
#pragma unroll
    for (int b = 0; b < 45; ++b) {
        float s = A[b];
        s += __shfl_down(s, 1, 64); s += __shfl_down(s, 2, 64);
        if (writer) ld[b * 64 + unit] = s;
    }
#pragma unroll
    for (int b = 0; b < 9; ++b) {
        float s = PA[b];
        s += __shfl_down(s, 1, 64); s += __shfl_down(s, 2, 64);
        if (writer) ld[(45 + b) * 64 + unit] = s;
    }
#pragma unroll
    for (int b = 0; b < 5; ++b) {
        float s = CNT[b];
        s += __shfl_down(s, 1, 64); s += __shfl_down(s, 2, 64);
        if (writer) ld[(54 + b) * 64 + unit] = s;
    }
    __syncthreads();

    // Threads 0..58: sum own row of 64 (rotated float4 reads), store
    // TRANSPOSED partial: bin-major, bx contiguous (coalesced finalize).
    if (tid < NBO) {
        const float4* row = (const float4*)(ld + tid * 64);
        float s = 0.0f;
#pragma unroll
        for (int i = 0; i < 16; ++i) {
            const float4 t4 = row[(i + tid) & 15];
            s += t4.x + t4.y + t4.z + t4.w;
        }
        ws[((size_t)img * NBO + tid) * BX + blockIdx.x] = s;
    }
}

__global__ __launch_bounds__(1024) void finalize_kernel(
    const float* __restrict__ ws, float* __restrict__ out)
{
    __shared__ float red[NIMG * NBO];   // 236
    __shared__ float contrib[NIMG];
    const int t = threadIdx.x;

    // 236 rows x 256 floats, contiguous: 4 threads/row, 16 float4 each.
    const int row = t >> 2, q = t & 3;
    if (row < NIMG * NBO) {
        const float4* basep = (const float4*)(ws + (size_t)row * BX + q * 64);
        float s = 0.0f;
#pragma unroll
        for (int i = 0; i < 16; ++i) {
            const float4 v = basep[i];
            s += v.x + v.y + v.z + v.w;
        }
        s += __shfl_down(s, 1, 64);
        s += __shfl_down(s, 2, 64);
        if (q == 0) red[row] = s;
    }
    __syncthreads();

    if (t < NIMG) {
        const float* b = red + t * NBO;
        // b[0..44]=inter(l-1,p-1), b[45..53]=pred_area(p-1), b[54..58]=label_area(l-1)
        float colsum[9];
#pragma unroll
        for (int p = 0; p < 9; ++p) colsum[p] = 0.0f;
        float pair_conn_sum = 0.0f;
        for (int l = 0; l < 5; ++l) {
            const float la = b[54 + l];
            float pc = 0.0f; int pn = 0;
            for (int p = 0; p < 9; ++p) {
                const float in = b[l * 9 + p];
                const float un = la + b[45 + p] - in;
                float iou;
                if (in == 0.0f)      iou = 0.0f;
                else if (un == 0.0f) iou = 1.0f;
                else                 iou = in / un;
                colsum[p] += iou;
                pc += iou;
                pn += (iou != 0.0f) ? 1 : 0;
            }
            if (pn > 0) pair_conn_sum += pc / (float)pn;
        }
        int lone = 0;
        for (int p = 0; p < 9; ++p) lone += (colsum[p] == 0.0f) ? 1 : 0;
        contrib[t] = 1.0f - pair_conn_sum / (5.0f + (float)lone);
    }
    __syncthreads();
    if (t == 0)
        out[0] = (contrib[0] + contrib[1] + contrib[2] + contrib[3]) * 0.25f;
}

extern "C" void kernel_launch(void* const* d_in, const int* in_sizes, int n_in,
                              void* d_out, int out_size, void* d_ws, size_t ws_size,
                              hipStream_t stream) {
    const float* pred  = (const float*)d_in[0];
    const int*   pconn = (const int*)d_in[1];
    const int*   lconn = (const int*)d_in[2];
    float* out = (float*)d_out;
    float* ws  = (float*)d_ws;

    dim3 grid(BX, NIMG);
    accum_kernel<<<grid, TPB, 0, stream>>>(pred, pconn, lconn, ws);

    finalize_kernel<<<1, 1024, 0, stream>>>(ws, out);
}